// Round 1
// baseline (396.268 us; speedup 1.0000x reference)
//
#include <hip/hip_runtime.h>
#include <hip/hip_bf16.h>
#include <cstdint>

// Problem: LSTMCell  B=8192, IN=1024, H=1024, fp32 in/out.
// Strategy:
//   1) cast_a: A = [x | h] -> bf16, shape [8192][2048] row-major.
//   2) cast_w: Bt = permuted-transposed weights -> bf16, shape [4096][2048]
//      row p = (j>>4)*64 + gate*16 + (j&15); Bt[p][k] = W_cat[k][col(gate,j)]
//      (gate: 0=i,1=f,2=g,3=o; k<1024 -> input weights, k>=1024 -> hidden)
//   3) lstm_gemm: G = A @ W_cat via bf16 MFMA 16x16x32, 128x128 tile, BK=32,
//      global_load_lds width=16 staging. Column permutation makes each lane
//      hold all 4 gates for its (row, j) -> fully lane-local fused epilogue:
//      new_c = sigmoid(i)... etc, write new_c, new_h directly. G never hits HBM.

#define B_DIM 8192
#define H_DIM 1024
#define K2    2048   // IN + H
#define N4    4096   // 4 * H

typedef __bf16 bf16x8 __attribute__((ext_vector_type(8)));
typedef __bf16 bf16x4 __attribute__((ext_vector_type(4)));
typedef float  f32x4  __attribute__((ext_vector_type(4)));

__device__ __forceinline__ void async_load16(const __bf16* g, __bf16* l) {
  __builtin_amdgcn_global_load_lds(
      (__attribute__((address_space(1))) void*)(g),
      (__attribute__((address_space(3))) void*)(l),
      16, 0, 0);
}

__device__ __forceinline__ float sigm(float x) {
  return 1.0f / (1.0f + __expf(-x));
}
__device__ __forceinline__ float tanh_fast(float x) {
  return 2.0f / (1.0f + __expf(-2.0f * x)) - 1.0f;
}

// ---------------- cast A = [x | h] -> bf16 [8192][2048] ----------------
__global__ void cast_a(const float* __restrict__ x, const float* __restrict__ h,
                       __bf16* __restrict__ A) {
  int tid = blockIdx.x * blockDim.x + threadIdx.x;  // 8192 * 512 threads
  int row = tid >> 9;        // 512 groups of 4 per row
  int k   = (tid & 511) << 2;
  const float* src = (k < H_DIM) ? (x + (size_t)row * H_DIM + k)
                                 : (h + (size_t)row * H_DIM + (k - H_DIM));
  float4 v = *(const float4*)src;
  bf16x4 o;
  o.x = (__bf16)v.x; o.y = (__bf16)v.y; o.z = (__bf16)v.z; o.w = (__bf16)v.w;
  *(bf16x4*)&A[(size_t)row * K2 + k] = o;
}

// ------------- cast + transpose + permute weights -> Bt [4096][2048] -------------
// grid: (K2/32, H/32, 4 gates), block 256
__global__ void cast_w(const float* __restrict__ Wii, const float* __restrict__ Wif,
                       const float* __restrict__ Wig, const float* __restrict__ Wio,
                       const float* __restrict__ Whi, const float* __restrict__ Whf,
                       const float* __restrict__ Whg, const float* __restrict__ Who,
                       __bf16* __restrict__ Bt) {
  __shared__ float tile[32][33];
  int k0 = blockIdx.x * 32;
  int j0 = blockIdx.y * 32;
  int gate = blockIdx.z;
  const float* Wi[4] = {Wii, Wif, Wig, Wio};
  const float* Wh[4] = {Whi, Whf, Whg, Who};
  const float* W = (k0 < H_DIM) ? Wi[gate] : Wh[gate];
  int kb = (k0 < H_DIM) ? k0 : (k0 - H_DIM);

  int tx = threadIdx.x & 31;
  int ty = threadIdx.x >> 5;  // 0..7
  for (int kk = ty; kk < 32; kk += 8)
    tile[kk][tx] = W[(size_t)(kb + kk) * H_DIM + j0 + tx];
  __syncthreads();
  for (int jj = ty; jj < 32; jj += 8) {
    int j = j0 + jj;
    int p = ((j >> 4) << 6) + (gate << 4) + (j & 15);
    Bt[(size_t)p * K2 + k0 + tx] = (__bf16)tile[tx][jj];
  }
}

// ---------------- fused GEMM + LSTM gate epilogue ----------------
// grid: (8192/128, 4096/128) = (64, 32), block 256 (4 waves)
__global__ __launch_bounds__(256) void lstm_gemm(
    const __bf16* __restrict__ A,    // [8192][2048]
    const __bf16* __restrict__ Bt,   // [4096][2048] permuted rows
    const float* __restrict__ c,
    const float* __restrict__ bi, const float* __restrict__ bf_,
    const float* __restrict__ bg, const float* __restrict__ bo,
    float* __restrict__ out_c, float* __restrict__ out_h) {
  __shared__ __align__(16) __bf16 As[128 * 32];
  __shared__ __align__(16) __bf16 Bs[128 * 32];

  const int tid  = threadIdx.x;
  const int wave = tid >> 6;
  const int lane = tid & 63;
  const int wm   = wave >> 1;      // 0..1 : M half
  const int wn   = wave & 1;       // 0..1 : N half
  const int m0   = blockIdx.x * 128;
  const int n0   = blockIdx.y * 128;

  f32x4 acc[4][4] = {};

  const int l15  = lane & 15;
  const int quad = lane >> 4;
  const int kseg = quad * 8;

  // staging: wave stages rows [32*wave, 32*wave+32) of both tiles
  const int srow0 = wave * 32 + (lane >> 2);         // chunk 2w
  const int srow1 = srow0 + 16;                      // chunk 2w+1
  const int sseg  = (lane & 3) * 8;                  // bf16 elems
  const __bf16* gA0 = A  + (size_t)(m0 + srow0) * K2 + sseg;
  const __bf16* gA1 = A  + (size_t)(m0 + srow1) * K2 + sseg;
  const __bf16* gB0 = Bt + (size_t)(n0 + srow0) * K2 + sseg;
  const __bf16* gB1 = Bt + (size_t)(n0 + srow1) * K2 + sseg;
  __bf16* lA0 = &As[(wave * 2 + 0) * 512];
  __bf16* lA1 = &As[(wave * 2 + 1) * 512];
  __bf16* lB0 = &Bs[(wave * 2 + 0) * 512];
  __bf16* lB1 = &Bs[(wave * 2 + 1) * 512];

  for (int k0 = 0; k0 < K2; k0 += 32) {
    __syncthreads();
    async_load16(gA0 + k0, lA0);
    async_load16(gA1 + k0, lA1);
    async_load16(gB0 + k0, lB0);
    async_load16(gB1 + k0, lB1);
    __syncthreads();

    bf16x8 af[4], bf8[4];
#pragma unroll
    for (int t = 0; t < 4; ++t)
      af[t] = *(const bf16x8*)&As[(wm * 64 + t * 16 + l15) * 32 + kseg];
#pragma unroll
    for (int t = 0; t < 4; ++t)
      bf8[t] = *(const bf16x8*)&Bs[(wn * 64 + t * 16 + l15) * 32 + kseg];

#pragma unroll
    for (int tm = 0; tm < 4; ++tm)
#pragma unroll
      for (int tn = 0; tn < 4; ++tn)
        acc[tm][tn] = __builtin_amdgcn_mfma_f32_16x16x32_bf16(
            af[tm], bf8[tn], acc[tm][tn], 0, 0, 0);
  }

  // epilogue: lane-local gates. j depends only on lane; gate == tn.
  const int j = blockIdx.y * 32 + wn * 16 + l15;
  const float vbi = bi[j], vbf = bf_[j], vbg = bg[j], vbo = bo[j];

#pragma unroll
  for (int tm = 0; tm < 4; ++tm) {
#pragma unroll
    for (int r = 0; r < 4; ++r) {
      int row = m0 + wm * 64 + tm * 16 + quad * 4 + r;
      float gi = sigm(acc[tm][0][r] + vbi);
      float gf = sigm(acc[tm][1][r] + vbf);
      float gg = tanh_fast(acc[tm][2][r] + vbg);
      float go = sigm(acc[tm][3][r] + vbo);
      size_t idx = (size_t)row * H_DIM + j;
      float cv = c[idx];
      float nc = gf * cv + gi * gg;
      float nh = go * tanh_fast(nc);
      out_c[idx] = nc;
      out_h[idx] = nh;
    }
  }
}

extern "C" void kernel_launch(void* const* d_in, const int* in_sizes, int n_in,
                              void* d_out, int out_size, void* d_ws, size_t ws_size,
                              hipStream_t stream) {
  const float* x   = (const float*)d_in[0];
  const float* c   = (const float*)d_in[1];
  const float* h   = (const float*)d_in[2];
  const float* Wii = (const float*)d_in[3];
  const float* Wif = (const float*)d_in[4];
  const float* Wig = (const float*)d_in[5];
  const float* Wio = (const float*)d_in[6];
  const float* Whi = (const float*)d_in[7];
  const float* Whf = (const float*)d_in[8];
  const float* Whg = (const float*)d_in[9];
  const float* Who = (const float*)d_in[10];
  const float* bi  = (const float*)d_in[11];
  const float* bf_ = (const float*)d_in[12];
  const float* bg  = (const float*)d_in[13];
  const float* bo  = (const float*)d_in[14];

  __bf16* Abf = (__bf16*)d_ws;                                  // 32 MiB
  __bf16* Bt  = (__bf16*)((char*)d_ws + (size_t)B_DIM * K2 * 2); // 16 MiB

  float* out_c = (float*)d_out;
  float* out_h = out_c + (size_t)B_DIM * H_DIM;

  cast_a<<<(B_DIM * K2 / 4) / 256, 256, 0, stream>>>(x, h, Abf);
  dim3 gw(K2 / 32, H_DIM / 32, 4);
  cast_w<<<gw, 256, 0, stream>>>(Wii, Wif, Wig, Wio, Whi, Whf, Whg, Who, Bt);
  dim3 gg(B_DIM / 128, N4 / 128);
  lstm_gemm<<<gg, 256, 0, stream>>>(Abf, Bt, c, bi, bf_, bg, bo, out_c, out_h);
}

// Round 2
// 367.207 us; speedup vs baseline: 1.0791x; 1.0791x over previous
//
#include <hip/hip_runtime.h>
#include <hip/hip_bf16.h>
#include <cstdint>

// LSTMCell B=8192, IN=H=1024, fp32 in/out.
// R2 changes vs R1:
//  - GEMM: BK 32->64 (32 KB LDS, barrier count halved, occupancy unchanged at
//    3 blocks/CU which is VGPR-limited), XOR-swizzled staging so fragment
//    ds_read_b128 is 2-way-per-bank-group (free) instead of 8-way.
//  - cast_a: 8 elem/thread, one block per row, wave-uniform x/h branch.
//  - cast_w: bf16x4 stores.

#define B_DIM 8192
#define H_DIM 1024
#define K2    2048   // IN + H
#define N4    4096   // 4 * H
#define BK    64

typedef __bf16 bf16x8 __attribute__((ext_vector_type(8)));
typedef __bf16 bf16x4 __attribute__((ext_vector_type(4)));
typedef float  f32x4  __attribute__((ext_vector_type(4)));

__device__ __forceinline__ void async_load16(const __bf16* g, __bf16* l) {
  __builtin_amdgcn_global_load_lds(
      (__attribute__((address_space(1))) void*)(g),
      (__attribute__((address_space(3))) void*)(l),
      16, 0, 0);
}

__device__ __forceinline__ float sigm(float x) {
  return 1.0f / (1.0f + __expf(-x));
}
__device__ __forceinline__ float tanh_fast(float x) {
  return 2.0f / (1.0f + __expf(-2.0f * x)) - 1.0f;
}

// ---------------- cast A = [x | h] -> bf16 [8192][2048] ----------------
// one block per row; threads 0..127 -> x, 128..255 -> h (wave-uniform branch)
__global__ void cast_a(const float* __restrict__ x, const float* __restrict__ h,
                       __bf16* __restrict__ A) {
  int row = blockIdx.x;
  int k = threadIdx.x << 3;  // 0..2040 step 8
  const float* src = (k < H_DIM) ? (x + (size_t)row * H_DIM + k)
                                 : (h + (size_t)row * H_DIM + (k - H_DIM));
  float4 v0 = *(const float4*)src;
  float4 v1 = *(const float4*)(src + 4);
  bf16x8 o;
  o[0] = (__bf16)v0.x; o[1] = (__bf16)v0.y; o[2] = (__bf16)v0.z; o[3] = (__bf16)v0.w;
  o[4] = (__bf16)v1.x; o[5] = (__bf16)v1.y; o[6] = (__bf16)v1.z; o[7] = (__bf16)v1.w;
  *(bf16x8*)&A[(size_t)row * K2 + k] = o;
}

// ------------- cast + transpose + permute weights -> Bt [4096][2048] -------------
// Bt row p = (j>>4)*64 + gate*16 + (j&15); Bt[p][k] = W_cat[k][gate-col j]
// grid: (K2/32, H/32, 4 gates), block 256
__global__ void cast_w(const float* __restrict__ Wii, const float* __restrict__ Wif,
                       const float* __restrict__ Wig, const float* __restrict__ Wio,
                       const float* __restrict__ Whi, const float* __restrict__ Whf,
                       const float* __restrict__ Whg, const float* __restrict__ Who,
                       __bf16* __restrict__ Bt) {
  __shared__ float tile[32][33];
  int k0 = blockIdx.x * 32;
  int j0 = blockIdx.y * 32;
  int gate = blockIdx.z;
  const float* Wi[4] = {Wii, Wif, Wig, Wio};
  const float* Wh[4] = {Whi, Whf, Whg, Who};
  const float* W = (k0 < H_DIM) ? Wi[gate] : Wh[gate];
  int kb = (k0 < H_DIM) ? k0 : (k0 - H_DIM);

  int tx = threadIdx.x & 31;
  int ty = threadIdx.x >> 5;  // 0..7
  for (int kk = ty; kk < 32; kk += 8)
    tile[kk][tx] = W[(size_t)(kb + kk) * H_DIM + j0 + tx];
  __syncthreads();

  int jj = threadIdx.x >> 3;   // 0..31
  int kq = threadIdx.x & 7;    // 0..7 (4 k's each)
  int j = j0 + jj;
  int p = ((j >> 4) << 6) + (gate << 4) + (j & 15);
  bf16x4 o;
  o[0] = (__bf16)tile[kq * 4 + 0][jj];
  o[1] = (__bf16)tile[kq * 4 + 1][jj];
  o[2] = (__bf16)tile[kq * 4 + 2][jj];
  o[3] = (__bf16)tile[kq * 4 + 3][jj];
  *(bf16x4*)&Bt[(size_t)p * K2 + k0 + kq * 4] = o;
}

// ---------------- fused GEMM + LSTM gate epilogue ----------------
// grid: (8192/128, 4096/128) = (64, 32), block 256 (4 waves)
// 128x128 tile, BK=64, 16x16x32 bf16 MFMA, 4x4 acc per wave.
__global__ __launch_bounds__(256) void lstm_gemm(
    const __bf16* __restrict__ A,    // [8192][2048]
    const __bf16* __restrict__ Bt,   // [4096][2048] permuted rows
    const float* __restrict__ c,
    const float* __restrict__ bi, const float* __restrict__ bf_,
    const float* __restrict__ bg, const float* __restrict__ bo,
    float* __restrict__ out_c, float* __restrict__ out_h) {
  // row stride = BK elems; row r, 16B-segment s (s=0..7) at elem r*64 + s*8.
  // Stored swizzled: slot s holds global segment s ^ (r&7).
  __shared__ __align__(16) __bf16 As[128 * BK];
  __shared__ __align__(16) __bf16 Bs[128 * BK];

  const int tid  = threadIdx.x;
  const int wave = tid >> 6;
  const int lane = tid & 63;
  const int wm   = wave >> 1;      // M half
  const int wn   = wave & 1;       // N half
  const int m0   = blockIdx.x * 128;
  const int n0   = blockIdx.y * 128;

  f32x4 acc[4][4] = {};

  const int l15  = lane & 15;
  const int quad = lane >> 4;

  // staging: chunk = 1 KiB = 8 rows x 64 elems. 16 chunks per tile.
  // wave w stages chunks [4w, 4w+4) of each tile.
  const int rin  = lane >> 3;                  // row within chunk 0..7
  const int slot = lane & 7;                   // LDS 16B slot within row
  const int sg   = slot ^ rin;                 // global segment (XOR swizzle)
  const __bf16* gA[4]; const __bf16* gB[4];
  __bf16* lA[4]; __bf16* lB[4];
#pragma unroll
  for (int c2 = 0; c2 < 4; ++c2) {
    int r = wave * 32 + c2 * 8 + rin;
    gA[c2] = A  + (size_t)(m0 + r) * K2 + sg * 8;
    gB[c2] = Bt + (size_t)(n0 + r) * K2 + sg * 8;
    lA[c2] = &As[(wave * 4 + c2) * 512];
    lB[c2] = &Bs[(wave * 4 + c2) * 512];
  }

  for (int k0 = 0; k0 < K2; k0 += BK) {
    __syncthreads();
#pragma unroll
    for (int c2 = 0; c2 < 4; ++c2) async_load16(gA[c2] + k0, lA[c2]);
#pragma unroll
    for (int c2 = 0; c2 < 4; ++c2) async_load16(gB[c2] + k0, lB[c2]);
    __syncthreads();

#pragma unroll
    for (int kk = 0; kk < 2; ++kk) {
      bf16x8 af[4], bfr[4];
      const int want = kk * 4 + quad;              // desired 16B segment
      const int sw   = (want ^ (l15 & 7)) * 8;     // swizzled elem offset
#pragma unroll
      for (int t = 0; t < 4; ++t)
        af[t] = *(const bf16x8*)&As[(wm * 64 + t * 16 + l15) * BK + sw];
#pragma unroll
      for (int t = 0; t < 4; ++t)
        bfr[t] = *(const bf16x8*)&Bs[(wn * 64 + t * 16 + l15) * BK + sw];

#pragma unroll
      for (int tm = 0; tm < 4; ++tm)
#pragma unroll
        for (int tn = 0; tn < 4; ++tn)
          acc[tm][tn] = __builtin_amdgcn_mfma_f32_16x16x32_bf16(
              af[tm], bfr[tn], acc[tm][tn], 0, 0, 0);
    }
  }

  // epilogue: lane-local gates. j depends only on lane; gate == tn.
  const int j = blockIdx.y * 32 + wn * 16 + l15;
  const float vbi = bi[j], vbf = bf_[j], vbg = bg[j], vbo = bo[j];

#pragma unroll
  for (int tm = 0; tm < 4; ++tm) {
#pragma unroll
    for (int r = 0; r < 4; ++r) {
      int row = m0 + wm * 64 + tm * 16 + quad * 4 + r;
      float gi = sigm(acc[tm][0][r] + vbi);
      float gf = sigm(acc[tm][1][r] + vbf);
      float gg = tanh_fast(acc[tm][2][r] + vbg);
      float go = sigm(acc[tm][3][r] + vbo);
      size_t idx = (size_t)row * H_DIM + j;
      float cv = c[idx];
      float nc = gf * cv + gi * gg;
      float nh = go * tanh_fast(nc);
      out_c[idx] = nc;
      out_h[idx] = nh;
    }
  }
}

extern "C" void kernel_launch(void* const* d_in, const int* in_sizes, int n_in,
                              void* d_out, int out_size, void* d_ws, size_t ws_size,
                              hipStream_t stream) {
  const float* x   = (const float*)d_in[0];
  const float* c   = (const float*)d_in[1];
  const float* h   = (const float*)d_in[2];
  const float* Wii = (const float*)d_in[3];
  const float* Wif = (const float*)d_in[4];
  const float* Wig = (const float*)d_in[5];
  const float* Wio = (const float*)d_in[6];
  const float* Whi = (const float*)d_in[7];
  const float* Whf = (const float*)d_in[8];
  const float* Whg = (const float*)d_in[9];
  const float* Who = (const float*)d_in[10];
  const float* bi  = (const float*)d_in[11];
  const float* bf_ = (const float*)d_in[12];
  const float* bg  = (const float*)d_in[13];
  const float* bo  = (const float*)d_in[14];

  __bf16* Abf = (__bf16*)d_ws;                                   // 32 MiB
  __bf16* Bt  = (__bf16*)((char*)d_ws + (size_t)B_DIM * K2 * 2); // 16 MiB

  float* out_c = (float*)d_out;
  float* out_h = out_c + (size_t)B_DIM * H_DIM;

  cast_a<<<B_DIM, 256, 0, stream>>>(x, h, Abf);
  dim3 gw(K2 / 32, H_DIM / 32, 4);
  cast_w<<<gw, 256, 0, stream>>>(Wii, Wif, Wig, Wio, Whi, Whf, Whg, Who, Bt);
  dim3 gg(B_DIM / 128, N4 / 128);
  lstm_gemm<<<gg, 256, 0, stream>>>(Abf, Bt, c, bi, bf_, bg, bo, out_c, out_h);
}

// Round 3
// 347.662 us; speedup vs baseline: 1.1398x; 1.0562x over previous
//
#include <hip/hip_runtime.h>
#include <hip/hip_bf16.h>
#include <cstdint>

// LSTMCell B=8192, IN=H=1024, fp32 in/out.
// R3 changes vs R2 (GEMM was LDS-BW-bound at 46 B/kFLOP, MfmaUtil 34%):
//  - 32x32x16 bf16 MFMA, wave tile 64x128 (2m x 4n of 32x32), block 128x256.
//    LDS traffic drops to 34 B/kFLOP, MFMA instr count halves.
//  - Gate permutation now p=(j>>5)*128+gate*32+(j&31): the 4 n-tiles of a
//    wave are the 4 gates for the same j -> lane-local fused epilogue kept.
//  - XOR-swizzled LDS staging kept (slot = seg ^ (row&7), 128B row stride).
//  - acc = 128 AGPR -> 2 waves/SIMD pinned via __launch_bounds__(256,2).

#define B_DIM 8192
#define H_DIM 1024
#define K2    2048   // IN + H
#define N4    4096   // 4 * H
#define BK    64
#define BM    128
#define BN    256

typedef __bf16 bf16x8 __attribute__((ext_vector_type(8)));
typedef __bf16 bf16x4 __attribute__((ext_vector_type(4)));
typedef float  f32x4  __attribute__((ext_vector_type(4)));
typedef float  f32x16 __attribute__((ext_vector_type(16)));

__device__ __forceinline__ void async_load16(const __bf16* g, __bf16* l) {
  __builtin_amdgcn_global_load_lds(
      (__attribute__((address_space(1))) void*)(g),
      (__attribute__((address_space(3))) void*)(l),
      16, 0, 0);
}

__device__ __forceinline__ float sigm(float x) {
  return 1.0f / (1.0f + __expf(-x));
}
__device__ __forceinline__ float tanh_fast(float x) {
  return 2.0f / (1.0f + __expf(-2.0f * x)) - 1.0f;
}

// ---------------- cast A = [x | h] -> bf16 [8192][2048] ----------------
__global__ void cast_a(const float* __restrict__ x, const float* __restrict__ h,
                       __bf16* __restrict__ A) {
  int row = blockIdx.x;
  int k = threadIdx.x << 3;  // 0..2040 step 8
  const float* src = (k < H_DIM) ? (x + (size_t)row * H_DIM + k)
                                 : (h + (size_t)row * H_DIM + (k - H_DIM));
  float4 v0 = *(const float4*)src;
  float4 v1 = *(const float4*)(src + 4);
  bf16x8 o;
  o[0] = (__bf16)v0.x; o[1] = (__bf16)v0.y; o[2] = (__bf16)v0.z; o[3] = (__bf16)v0.w;
  o[4] = (__bf16)v1.x; o[5] = (__bf16)v1.y; o[6] = (__bf16)v1.z; o[7] = (__bf16)v1.w;
  *(bf16x8*)&A[(size_t)row * K2 + k] = o;
}

// ------------- cast + transpose + permute weights -> Bt [4096][2048] -------------
// Bt row p = (j>>5)*128 + gate*32 + (j&31); Bt[p][k] = W_cat[k][gate-col j]
// grid: (K2/64, H/32, 4 gates), block 256
__global__ void cast_w(const float* __restrict__ Wii, const float* __restrict__ Wif,
                       const float* __restrict__ Wig, const float* __restrict__ Wio,
                       const float* __restrict__ Whi, const float* __restrict__ Whf,
                       const float* __restrict__ Whg, const float* __restrict__ Who,
                       __bf16* __restrict__ Bt) {
  __shared__ float tile[64][33];
  int k0 = blockIdx.x * 64;
  int j0 = blockIdx.y * 32;
  int gate = blockIdx.z;
  const float* Wi[4] = {Wii, Wif, Wig, Wio};
  const float* Wh[4] = {Whi, Whf, Whg, Who};
  const float* W = (k0 < H_DIM) ? Wi[gate] : Wh[gate];
  int kb = (k0 < H_DIM) ? k0 : (k0 - H_DIM);

  int col = threadIdx.x & 31;
  int rr  = threadIdx.x >> 5;  // 0..7
#pragma unroll
  for (int p = 0; p < 8; ++p)
    tile[p * 8 + rr][col] = W[(size_t)(kb + p * 8 + rr) * H_DIM + j0 + col];
  __syncthreads();

  int jj = threadIdx.x >> 3;   // 0..31
  int ko = threadIdx.x & 7;    // 0..7 (8 k's each)
  int j = j0 + jj;
  int p = ((j >> 5) << 7) + (gate << 5) + (j & 31);
  bf16x8 o;
#pragma unroll
  for (int t = 0; t < 8; ++t) o[t] = (__bf16)tile[ko * 8 + t][jj];
  *(bf16x8*)&Bt[(size_t)p * K2 + k0 + ko * 8] = o;
}

// ---------------- fused GEMM + LSTM gate epilogue ----------------
// grid: (8192/128, 4096/256) = (64, 16), block 256 (4 waves)
// block tile 128x256, wave tile 64x128 (2m x 4n of 32x32), BK=64.
__global__ __launch_bounds__(256, 2) void lstm_gemm(
    const __bf16* __restrict__ A,    // [8192][2048]
    const __bf16* __restrict__ Bt,   // [4096][2048] permuted rows
    const float* __restrict__ c,
    const float* __restrict__ bi, const float* __restrict__ bf_,
    const float* __restrict__ bg, const float* __restrict__ bo,
    float* __restrict__ out_c, float* __restrict__ out_h) {
  // row stride BK elems = 128 B = 8 x 16B slots; physical slot s of row r
  // holds global segment s ^ (r&7).
  __shared__ __align__(16) __bf16 As[BM * BK];   // 16 KB
  __shared__ __align__(16) __bf16 Bs[BN * BK];   // 32 KB

  const int tid  = threadIdx.x;
  const int wave = tid >> 6;
  const int lane = tid & 63;
  const int wm   = wave >> 1;      // 0..1 : M half (64 rows)
  const int wn   = wave & 1;       // 0..1 : N half (128 perm-cols)
  const int m0   = blockIdx.x * BM;
  const int n0   = blockIdx.y * BN;

  f32x16 acc[2][4] = {};

  const int l31 = lane & 31;
  const int h8  = lane >> 5;       // k-half within K=16 step

  // staging: chunk = 8 rows x 64 elems = 1 KiB. A:16 chunks, B:32 chunks.
  const int rin  = lane >> 3;                  // row in chunk 0..7
  const int slot = lane & 7;                   // LDS 16B slot
  const int sg   = slot ^ rin;                 // global segment (XOR swizzle)
  const __bf16* gA[4]; const __bf16* gB[8];
  __bf16* lA[4]; __bf16* lB[8];
#pragma unroll
  for (int cc = 0; cc < 4; ++cc) {
    int r = wave * 32 + cc * 8 + rin;
    gA[cc] = A + (size_t)(m0 + r) * K2 + sg * 8;
    lA[cc] = &As[(wave * 4 + cc) * 512];
  }
#pragma unroll
  for (int cc = 0; cc < 8; ++cc) {
    int r = wave * 64 + cc * 8 + rin;
    gB[cc] = Bt + (size_t)(n0 + r) * K2 + sg * 8;
    lB[cc] = &Bs[(wave * 8 + cc) * 512];
  }

  for (int k0 = 0; k0 < K2; k0 += BK) {
    __syncthreads();
#pragma unroll
    for (int cc = 0; cc < 4; ++cc) async_load16(gA[cc] + k0, lA[cc]);
#pragma unroll
    for (int cc = 0; cc < 8; ++cc) async_load16(gB[cc] + k0, lB[cc]);
    __syncthreads();

#pragma unroll
    for (int ks = 0; ks < 4; ++ks) {
      bf16x8 af[2], bfr[4];
      const int sw = ((ks * 2 + h8) ^ (l31 & 7)) * 8;  // swizzled elem offset
#pragma unroll
      for (int t = 0; t < 2; ++t)
        af[t] = *(const bf16x8*)&As[(wm * 64 + t * 32 + l31) * BK + sw];
#pragma unroll
      for (int t = 0; t < 4; ++t)
        bfr[t] = *(const bf16x8*)&Bs[(wn * 128 + t * 32 + l31) * BK + sw];

#pragma unroll
      for (int tm = 0; tm < 2; ++tm)
#pragma unroll
        for (int tn = 0; tn < 4; ++tn)
          acc[tm][tn] = __builtin_amdgcn_mfma_f32_32x32x16_bf16(
              af[tm], bfr[tn], acc[tm][tn], 0, 0, 0);
    }
  }

  // epilogue: lane-local gates, gate == tn.
  // j = (perm-group) * 32 + (lane&31); perm-group = blockIdx.y*2 + wn
  const int j = blockIdx.y * 64 + wn * 32 + l31;
  const float vbi = bi[j], vbf = bf_[j], vbg = bg[j], vbo = bo[j];

#pragma unroll
  for (int tm = 0; tm < 2; ++tm) {
#pragma unroll
    for (int r = 0; r < 16; ++r) {
      int row = m0 + wm * 64 + tm * 32 + 4 * h8 + (r & 3) + 8 * (r >> 2);
      float gi = sigm(acc[tm][0][r] + vbi);
      float gf = sigm(acc[tm][1][r] + vbf);
      float gg = tanh_fast(acc[tm][2][r] + vbg);
      float go = sigm(acc[tm][3][r] + vbo);
      size_t idx = (size_t)row * H_DIM + j;
      float cv = c[idx];
      float nc = gf * cv + gi * gg;
      float nh = go * tanh_fast(nc);
      out_c[idx] = nc;
      out_h[idx] = nh;
    }
  }
}

extern "C" void kernel_launch(void* const* d_in, const int* in_sizes, int n_in,
                              void* d_out, int out_size, void* d_ws, size_t ws_size,
                              hipStream_t stream) {
  const float* x   = (const float*)d_in[0];
  const float* c   = (const float*)d_in[1];
  const float* h   = (const float*)d_in[2];
  const float* Wii = (const float*)d_in[3];
  const float* Wif = (const float*)d_in[4];
  const float* Wig = (const float*)d_in[5];
  const float* Wio = (const float*)d_in[6];
  const float* Whi = (const float*)d_in[7];
  const float* Whf = (const float*)d_in[8];
  const float* Whg = (const float*)d_in[9];
  const float* Who = (const float*)d_in[10];
  const float* bi  = (const float*)d_in[11];
  const float* bf_ = (const float*)d_in[12];
  const float* bg  = (const float*)d_in[13];
  const float* bo  = (const float*)d_in[14];

  __bf16* Abf = (__bf16*)d_ws;                                   // 32 MiB
  __bf16* Bt  = (__bf16*)((char*)d_ws + (size_t)B_DIM * K2 * 2); // 16 MiB

  float* out_c = (float*)d_out;
  float* out_h = out_c + (size_t)B_DIM * H_DIM;

  cast_a<<<B_DIM, 256, 0, stream>>>(x, h, Abf);
  dim3 gw(K2 / 64, H_DIM / 32, 4);
  cast_w<<<gw, 256, 0, stream>>>(Wii, Wif, Wig, Wio, Whi, Whf, Whg, Who, Bt);
  dim3 gg(B_DIM / BM, N4 / BN);
  lstm_gemm<<<gg, 256, 0, stream>>>(Abf, Bt, c, bi, bf_, bg, bo, out_c, out_h);
}